// Round 1
// baseline (246.351 us; speedup 1.0000x reference)
//
#include <hip/hip_runtime.h>

// Problem constants (B,C,H,W = 32,64,128,128)
static constexpr int Cc  = 64;
static constexpr int HWc = 16384;   // 128*128
static constexpr int Bc  = 32;
static constexpr int NT  = 128;     // pixels per tile
static constexpr int TPB = 4;       // tiles per block (software pipeline)

// ---------------------------------------------------------------------------
// Identity (verified): sigmoid(d)+sigmoid(-d)=1 makes A[b] = -0.5*theta, so
// out[b,n,:] = W_lin @ relu(-0.5*theta @ x[b,:,n]) + b_lin.
// Round 3: latency-bound fix.
//  - GEMM1 SWAPPED: D = M1 @ x  (A=M1 frag, B=x frag) -> lane holds
//    P[n=lq][i=quad*4+r] : 4 consecutive i -> relu+pack -> ds_write_b64 (16/lane
//    instead of 64 scalar u16 writes). p2 is PER-WAVE -> zero barriers needed.
//  - GEMM2 SWAPPED: D = W @ P^T -> lane holds out[n=lq][c=quad*4+r] : 4
//    consecutive c -> float4 stores (16/lane instead of 64 scalar stores).
//  - 4-tile pipeline per block, double-buffered x tile in LDS, register
//    prefetch of tile t+1 issued before GEMM1(t); ONE barrier per tile.
// mfma_f32_16x16x32_f16 layouts (HW-verified):
//   A[m=lane&15][k=quad*8+j]  B[col=lane&15][k=quad*8+j]  D[row=quad*4+r][col=lane&15]
// ---------------------------------------------------------------------------

typedef _Float16 v8h __attribute__((ext_vector_type(8)));
typedef float    v4f __attribute__((ext_vector_type(4)));

union FragU { uint32_t u[4]; v8h h; };

__device__ inline uint32_t packf2(float lo, float hi) {
  union { _Float16 h[2]; uint32_t u; } r;
  r.h[0] = (_Float16)lo; r.h[1] = (_Float16)hi;
  return r.u;
}

__device__ inline v4f mfma16(v8h a, v8h b, v4f c) {
  return __builtin_amdgcn_mfma_f32_16x16x32_f16(a, b, c, 0, 0, 0);
}

// Prep: f16 weights. M1h = -0.5*theta (row-major [i][c]); Wh = W_lin ([c][i]).
__global__ void prep_weights(const float* __restrict__ theta,
                             const float* __restrict__ Wlin,
                             _Float16* __restrict__ M1h,
                             _Float16* __restrict__ Wh) {
  int t = blockIdx.x * 256 + threadIdx.x;
  if (t < Cc * Cc) {
    M1h[t] = (_Float16)(-0.5f * theta[t]);
    Wh[t]  = (_Float16)(Wlin[t]);
  }
}

__global__ __launch_bounds__(256, 3) void fused_mfma(
    const float* __restrict__ x,      // [B, C, HW]
    const _Float16* __restrict__ M1h, // [64][64]
    const _Float16* __restrict__ Wh,  // [64][64]
    const float* __restrict__ blin,   // [64]
    float* __restrict__ out)          // [B, HW, C]
{
  // xp: double-buffered x tile as f16x2 channel pairs, xp[buf][p][n].
  //     row stride 132 dwords -> frag-read banks (16*quad+4r+lq)%32 = 2-way (free).
  // p2: per-wave P tile [32 n][64+8 i] f16; stride 72 -> 16B-aligned b128 reads.
  //     p2[wv] is private to wave wv -> in-wave lgkmcnt ordering only, NO barrier.
  __shared__ __align__(16) uint32_t  xp[2][32][132];   // 33792 B
  __shared__ __align__(16) _Float16  p2[4][32][72];    // 18432 B

  const int tid   = threadIdx.x;
  const int tile0 = blockIdx.x * TPB;
  const int b     = tile0 >> 7;           // 128 tiles per batch; 4-tile groups never straddle
  const int n00   = (tile0 & 127) * NT;
  const float* xb = x + (size_t)b * Cc * HWc;

  const int wv   = tid >> 6;        // wave 0..3, owns pixels [wv*32, wv*32+32)
  const int lq   = tid & 15;
  const int quad = (tid & 63) >> 4;
  const int nw   = wv * 32;

  const int sp   = tid >> 5;        // staging pair-subrow 0..7
  const int scol = (tid & 31) * 4;  // staging col (dwords)

  // ---- prologue: stage tile 0 into xp[0] (coalesced float4, pack to f16 pairs)
  {
    const float* xt = xb + n00;
#pragma unroll
    for (int rep = 0; rep < 4; ++rep) {
      const int p = rep * 8 + sp;
      const float4 e = *(const float4*)(xt + (size_t)(2 * p)     * HWc + scol);
      const float4 o = *(const float4*)(xt + (size_t)(2 * p + 1) * HWc + scol);
      uint4 w;
      w.x = packf2(e.x, o.x); w.y = packf2(e.y, o.y);
      w.z = packf2(e.z, o.z); w.w = packf2(e.w, o.w);
      *(uint4*)&xp[0][p][scol] = w;
    }
  }

  // ---- hoisted weight frags (L2-resident, loop-invariant)
  const v8h* M1v = (const v8h*)M1h;
  const v8h* Whv = (const v8h*)Wh;
  v8h w1[4][2], w2[4][2];
#pragma unroll
  for (int it = 0; it < 4; ++it)
#pragma unroll
    for (int kt = 0; kt < 2; ++kt) {
      w1[it][kt] = M1v[(it * 16 + lq) * 8 + kt * 4 + quad];  // M1[i][c] A-frag
      w2[it][kt] = Whv[(it * 16 + lq) * 8 + kt * 4 + quad];  // W[c][i]  A-frag
    }
  v4f bias4[4];
#pragma unroll
  for (int ct = 0; ct < 4; ++ct)
    bias4[ct] = *(const v4f*)(blin + ct * 16 + quad * 4);

  __syncthreads();

#pragma unroll
  for (int t = 0; t < TPB; ++t) {
    const int cur = t & 1;

    // ---- issue next tile's global loads FIRST (latency hidden under GEMMs)
    float4 pf[8];
    if (t < TPB - 1) {
      const float* xt = xb + n00 + (t + 1) * NT;
#pragma unroll
      for (int rep = 0; rep < 4; ++rep) {
        const int p = rep * 8 + sp;
        pf[2 * rep]     = *(const float4*)(xt + (size_t)(2 * p)     * HWc + scol);
        pf[2 * rep + 1] = *(const float4*)(xt + (size_t)(2 * p + 1) * HWc + scol);
      }
    }

    // ---- x frags (B-operand) from xp[cur]: u32 r = channel-pair kt*16+quad*4+r
    FragU xf[2][2];
#pragma unroll
    for (int nt = 0; nt < 2; ++nt)
#pragma unroll
      for (int kt = 0; kt < 2; ++kt)
#pragma unroll
        for (int r = 0; r < 4; ++r)
          xf[nt][kt].u[r] = xp[cur][kt * 16 + quad * 4 + r][nw + nt * 16 + lq];

    // ---- GEMM1 (swapped): D1[i][n] = M1 @ x ; lane -> P[n=nt*16+lq][i=it*16+quad*4+r]
    //      relu + pack pairs -> one b64 write per (it,nt)
#pragma unroll
    for (int it = 0; it < 4; ++it)
#pragma unroll
      for (int nt = 0; nt < 2; ++nt) {
        v4f a = {0.f, 0.f, 0.f, 0.f};
#pragma unroll
        for (int kt = 0; kt < 2; ++kt)
          a = mfma16(w1[it][kt], xf[nt][kt].h, a);
        uint2 w;
        w.x = packf2(fmaxf(a[0], 0.f), fmaxf(a[1], 0.f));
        w.y = packf2(fmaxf(a[2], 0.f), fmaxf(a[3], 0.f));
        *(uint2*)&p2[wv][nt * 16 + lq][it * 16 + quad * 4] = w;
      }

    // ---- GEMM2 (swapped): D2[c][n] = W @ P^T ; lane -> out[n=nt*16+lq][c=ct*16+quad*4+r]
    //      -> float4 stores along c (1 KB/instr coalescing)
    const size_t orow0 = ((size_t)b * HWc + n00 + t * NT + nw) * Cc;
#pragma unroll
    for (int nt = 0; nt < 2; ++nt) {
      FragU pr[2];
#pragma unroll
      for (int kt = 0; kt < 2; ++kt)
        pr[kt].h = *(const v8h*)&p2[wv][nt * 16 + lq][kt * 32 + quad * 8];
      float* orow = out + orow0 + (size_t)(nt * 16 + lq) * Cc + quad * 4;
#pragma unroll
      for (int ct = 0; ct < 4; ++ct) {
        v4f a = bias4[ct];
#pragma unroll
        for (int kt = 0; kt < 2; ++kt)
          a = mfma16(w2[ct][kt], pr[kt].h, a);
        *(v4f*)(orow + ct * 16) = a;
      }
    }

    // ---- drain prefetch, pack, write other buffer; one barrier per tile.
    // xp[cur^1] was last read at iteration t-1, separated by that iteration's
    // barrier -> safe to overwrite here.
    if (t < TPB - 1) {
#pragma unroll
      for (int rep = 0; rep < 4; ++rep) {
        const int p = rep * 8 + sp;
        uint4 w;
        w.x = packf2(pf[2 * rep].x, pf[2 * rep + 1].x);
        w.y = packf2(pf[2 * rep].y, pf[2 * rep + 1].y);
        w.z = packf2(pf[2 * rep].z, pf[2 * rep + 1].z);
        w.w = packf2(pf[2 * rep].w, pf[2 * rep + 1].w);
        *(uint4*)&xp[cur ^ 1][p][scol] = w;
      }
      __syncthreads();
    }
  }
}

extern "C" void kernel_launch(void* const* d_in, const int* in_sizes, int n_in,
                              void* d_out, int out_size, void* d_ws, size_t ws_size,
                              hipStream_t stream) {
  const float* x     = (const float*)d_in[0];
  const float* theta = (const float*)d_in[1];
  const float* W_lin = (const float*)d_in[2];
  const float* b_lin = (const float*)d_in[3];
  float* out = (float*)d_out;

  _Float16* M1h = (_Float16*)d_ws;
  _Float16* Wh  = M1h + Cc * Cc;

  prep_weights<<<(Cc * Cc + 255) / 256, 256, 0, stream>>>(theta, W_lin, M1h, Wh);

  const int nblocks = Bc * HWc / (NT * TPB);   // 1024
  fused_mfma<<<nblocks, 256, 0, stream>>>(x, M1h, Wh, b_lin, out);
}